// Round 1
// 566.190 us; speedup vs baseline: 1.1577x; 1.1577x over previous
//
#include <hip/hip_runtime.h>
#include <hip/hip_bf16.h>

// Bahdanau additive attention, MI355X. B=32, S=2048, E=D=1024. M = B*S = 65536.
// scores[m] = v . tanh(enc[m,:] @ w1 + qq[b]),  qq[b] = dec[b] @ w2 + b2 + b1
// (bv dropped: softmax-invariant). attn = softmax_s(scores); context[b] = attn[b,:] @ enc[b,:,:]
//
// Round-6 structure: A-RESIDENT, BARRIER-FREE GEMM.
// Each block owns 64 m-rows and the FULL N=1024 / K=1024 sweep:
//   - enc[64 rows][1024 k] converted fp32->bf16 ONCE into a 128 KiB LDS image
//     (vs 8x redundant convert at 128-wide n-tiles). One __syncthreads total.
//   - w1 pre-packed FRAGMENT-LINEAR: frag(kt,nt) = 1 KiB, lane l holds
//     B[n=nt*16+(l&15)][k=kt*32+(l>>4)*8+j] as 16 contiguous bytes ->
//     B operand loads are single coalesced global_load_dwordx4 straight from
//     L2 (w1p = 2 MB, L2-resident) into registers. No B LDS, no barriers.
//   - 8 waves x n-strip 128: per k32-step 4 ds_read (A) + 8 L2 loads (B,
//     double-buffered 1 step ahead) + 32 MFMA -> MFMA-dominant budget.
// LDS swizzle (verified 0-conflict rounds 2-5): row = 2048 B = 128 chunks of
// 16 B; logical chunk c stored at (c&~7)|((c^r)&7). Both ds_write_b128
// staging (8 lanes/row cover one 128 B window) and ds_read_b128 fragment
// reads (each 8-lane phase hits 8 distinct chunks) are conflict-free.

typedef __attribute__((ext_vector_type(8))) short short8;   // 8 bf16 (4 VGPRs)
typedef __attribute__((ext_vector_type(4))) float f32x4;    // MFMA acc

#define M_TOTAL 65536
#define KDIM    1024

// pack two fp32 -> two bf16 (round-half-up) in one dword: 2 adds + 1 v_perm
static __device__ inline unsigned int pk2h(float a, float b) {
    unsigned int ua = __builtin_bit_cast(unsigned int, a) + 0x8000u;
    unsigned int ub = __builtin_bit_cast(unsigned int, b) + 0x8000u;
    return __builtin_amdgcn_perm(ub, ua, 0x07060302u);
}

// ---- w1 [d=k][e=n] fp32 -> fragment-linear bf16 image ----
// frag index = kt*64 + nt  (kt = k/32 in 0..31, nt = n/16 in 0..63)
// within frag: lane l, elem j = w1[kt*32 + (l>>4)*8 + j][nt*16 + (l&15)]
// -> 1 KiB per frag, each lane's 8 bf16 contiguous (one dwordx4 per load).
__global__ __launch_bounds__(64) void pack_w1(const float* __restrict__ w1,
                                              unsigned short* __restrict__ w1p) {
    const int nt = blockIdx.x;       // 0..63
    const int kt = blockIdx.y;       // 0..31
    const int l  = threadIdx.x;      // 0..63
    const int n  = nt * 16 + (l & 15);
    const int kb = kt * 32 + (l >> 4) * 8;
    const float* s = w1 + (size_t)kb * 1024 + n;
    uint4 wv;
    wv.x = pk2h(s[0],    s[1024]);
    wv.y = pk2h(s[2048], s[3072]);
    wv.z = pk2h(s[4096], s[5120]);
    wv.w = pk2h(s[6144], s[7168]);
    *reinterpret_cast<uint4*>(w1p + (((size_t)(kt * 64 + nt)) << 9) + (l << 3)) = wv;
}

// ---- qq[b][e] += partial of b1+b2 + dec[b]@w2, split-k x4 ----
__global__ __launch_bounds__(256) void qq_kern(const float* __restrict__ dec,
                                               const float* __restrict__ w2,
                                               const float* __restrict__ b1,
                                               const float* __restrict__ b2,
                                               float* __restrict__ qq) {
    const int b = blockIdx.y;
    const int e = blockIdx.x * 256 + threadIdx.x;
    const int d0 = blockIdx.z * 256;
    const float* db = dec + b * 1024;
    float acc = (blockIdx.z == 0) ? (b1[e] + b2[e]) : 0.f;
#pragma unroll 8
    for (int d = d0; d < d0 + 256; d++)
        acc = fmaf(db[d], w2[d * 1024 + e], acc);
    atomicAdd(&qq[b * 1024 + e], acc);
}

// ---- fused GEMM: A-panel resident in LDS, B streamed L2->regs ----
__global__ __launch_bounds__(512, 2) void score_gemm(const float* __restrict__ enc,
                                                     const unsigned short* __restrict__ w1p,
                                                     const float* __restrict__ qq,
                                                     const float* __restrict__ vvec,
                                                     float* __restrict__ scores) {
    __shared__ __align__(16) unsigned short As[64 * 1024];   // 128 KiB

    const int m0 = blockIdx.x << 6;       // 64 m-rows per block, 1024 blocks
    const int b = m0 >> 11;
    const int tid = threadIdx.x;
    const int wid = tid >> 6;             // 0..7, n-strip = wid*128
    const int lane = tid & 63;
    const int quad = lane >> 4, lc = lane & 15;

    // ---- prologue: stage A = enc[m0..m0+64) x 1024, fp32 -> bf16, ONCE ----
    {
        const int r  = tid >> 3;          // 0..63 row
        const int c8 = tid & 7;           // chunk within 128 B window
        const int sw = c8 ^ (r & 7);      // swizzled chunk slot
        const float* src0 = enc + (size_t)(m0 + r) * 1024 + (c8 << 3);
        unsigned short* dst0 = As + (r << 10) + (sw << 3);
#pragma unroll 4
        for (int w = 0; w < 16; w++) {
            const float* s = src0 + (w << 6);
            float4 f0 = *reinterpret_cast<const float4*>(s);
            float4 f1 = *reinterpret_cast<const float4*>(s + 4);
            uint4 pv;
            pv.x = pk2h(f0.x, f0.y);
            pv.y = pk2h(f0.z, f0.w);
            pv.z = pk2h(f1.x, f1.y);
            pv.w = pk2h(f1.z, f1.w);
            *reinterpret_cast<uint4*>(dst0 + (w << 6)) = pv;
        }
    }

    f32x4 acc[4][8];
#pragma unroll
    for (int mi = 0; mi < 4; mi++)
#pragma unroll
        for (int ni = 0; ni < 8; ni++)
            acc[mi][ni] = (f32x4){0.f, 0.f, 0.f, 0.f};

    __syncthreads();   // the ONLY barrier: As ready, read-only afterwards

    // B fragment stream base for this wave: frags (kt*64 + wid*8 + ni)
    // short offset = kt*32768 + wid*4096 + ni*512 + lane*8
    const unsigned short* bb = w1p + ((size_t)wid << 12) + (lane << 3);

    short8 bA[8], bB[8];
#pragma unroll
    for (int ni = 0; ni < 8; ni++)
        bA[ni] = *reinterpret_cast<const short8*>(bb + ni * 512);

    for (int kt = 0; kt < 32; kt += 2) {
        // prefetch kt+1 into bB (L2 latency hides under this step's MFMAs)
#pragma unroll
        for (int ni = 0; ni < 8; ni++)
            bB[ni] = *reinterpret_cast<const short8*>(bb + (kt + 1) * 32768 + ni * 512);

        short8 af[4];
        {
            const int c = kt * 4 + quad;                   // logical 16B chunk
            const int off = ((c & ~7) | ((c ^ lc) & 7)) << 3;
#pragma unroll
            for (int mi = 0; mi < 4; mi++)
                af[mi] = *reinterpret_cast<const short8*>(&As[((mi * 16 + lc) << 10) + off]);
        }
        __builtin_amdgcn_s_setprio(1);
#pragma unroll
        for (int mi = 0; mi < 4; mi++)
#pragma unroll
            for (int ni = 0; ni < 8; ni++)
                acc[mi][ni] = __builtin_amdgcn_mfma_f32_16x16x32_bf16(af[mi], bA[ni], acc[mi][ni], 0, 0, 0);
        __builtin_amdgcn_s_setprio(0);

        // prefetch kt+2 into bA
        if (kt < 30) {
#pragma unroll
            for (int ni = 0; ni < 8; ni++)
                bA[ni] = *reinterpret_cast<const short8*>(bb + (kt + 2) * 32768 + ni * 512);
        }
        {
            const int c = kt * 4 + 4 + quad;
            const int off = ((c & ~7) | ((c ^ lc) & 7)) << 3;
#pragma unroll
            for (int mi = 0; mi < 4; mi++)
                af[mi] = *reinterpret_cast<const short8*>(&As[((mi * 16 + lc) << 10) + off]);
        }
        __builtin_amdgcn_s_setprio(1);
#pragma unroll
        for (int mi = 0; mi < 4; mi++)
#pragma unroll
            for (int ni = 0; ni < 8; ni++)
                acc[mi][ni] = __builtin_amdgcn_mfma_f32_16x16x32_bf16(af[mi], bB[ni], acc[mi][ni], 0, 0, 0);
        __builtin_amdgcn_s_setprio(0);
    }

    // ---- epilogue: tanh(C + qq)*v, reduce over this wave's 128 n ----
    // acc[mi][ni][r] = C[m = mi*16 + quad*4 + r][n = wid*128 + ni*16 + lc]
    const float* qb = qq + (b << 10) + (wid << 7) + lc;
    const float* vb = vvec + (wid << 7) + lc;
    float qn[8], vn[8];
#pragma unroll
    for (int ni = 0; ni < 8; ni++) {
        qn[ni] = qb[ni << 4];
        vn[ni] = vb[ni << 4];
    }
    float red[16];
#pragma unroll
    for (int mi = 0; mi < 4; mi++) {
#pragma unroll
        for (int r = 0; r < 4; r++) {
            float ssum = 0.f;
#pragma unroll
            for (int ni = 0; ni < 8; ni++) {
                float x = acc[mi][ni][r] + qn[ni];
                float e = __expf(2.0f * x);          // overflow-safe tanh
                float th = 1.0f - 2.0f / (e + 1.0f);
                ssum = fmaf(th, vn[ni], ssum);
            }
            float t = ssum;
            t += __shfl_xor(t, 1);
            t += __shfl_xor(t, 2);
            t += __shfl_xor(t, 4);
            t += __shfl_xor(t, 8);
            red[mi * 4 + r] = t;
        }
    }
    float myv = red[0];
#pragma unroll
    for (int i = 1; i < 16; i++)
        if (lc == i) myv = red[i];
    // lane (quad,lc) owns m = (lc>>2)*16 + quad*4 + (lc&3); 8 waves atomic-add
    atomicAdd(scores + m0 + (lc >> 2) * 16 + quad * 4 + (lc & 3), myv);
}

// ---- softmax over s (2048) per batch ----
__global__ __launch_bounds__(256) void softmax_kern(const float* __restrict__ scores,
                                                    float* __restrict__ attn) {
    const int b = blockIdx.x;
    const int tid = threadIdx.x;
    const int wid = tid >> 6, lane = tid & 63;
    const float* s = scores + b * 2048;
    float x[8];
    float m = -1e30f;
#pragma unroll
    for (int i = 0; i < 8; i++) {
        x[i] = s[tid + i * 256];
        m = fmaxf(m, x[i]);
    }
    for (int off = 1; off < 64; off <<= 1) m = fmaxf(m, __shfl_xor(m, off));
    __shared__ float redm[4];
    if (lane == 0) redm[wid] = m;
    __syncthreads();
    m = fmaxf(fmaxf(redm[0], redm[1]), fmaxf(redm[2], redm[3]));
    float sum = 0.f;
#pragma unroll
    for (int i = 0; i < 8; i++) {
        x[i] = __expf(x[i] - m);
        sum += x[i];
    }
    for (int off = 1; off < 64; off <<= 1) sum += __shfl_xor(sum, off);
    __shared__ float reds[4];
    if (lane == 0) reds[wid] = sum;
    __syncthreads();
    sum = reds[0] + reds[1] + reds[2] + reds[3];
    const float inv = 1.0f / sum;
#pragma unroll
    for (int i = 0; i < 8; i++) attn[b * 2048 + tid + i * 256] = x[i] * inv;
}

// ---- context[b][e] = sum_s attn[b][s] * enc[b][s][e] ----
__global__ __launch_bounds__(256) void ctx_kern(const float* __restrict__ attn,
                                                const float* __restrict__ enc,
                                                float* __restrict__ out) {
    const int b = blockIdx.y;
    const int sc = blockIdx.x;    // 32 chunks x 64 s
    const int tid = threadIdx.x;
    const float* ab = attn + b * 2048 + sc * 64;
    const float* eb = enc + ((size_t)b * 2048 + sc * 64) * 1024 + tid * 4;
    float4 acc = {0.f, 0.f, 0.f, 0.f};
#pragma unroll 16
    for (int s = 0; s < 64; s++) {
        float w = ab[s];
        float4 ev = *reinterpret_cast<const float4*>(eb + (size_t)s * 1024);
        acc.x = fmaf(w, ev.x, acc.x);
        acc.y = fmaf(w, ev.y, acc.y);
        acc.z = fmaf(w, ev.z, acc.z);
        acc.w = fmaf(w, ev.w, acc.w);
    }
    float* op = out + b * 1024 + tid * 4;
    atomicAdd(op + 0, acc.x);
    atomicAdd(op + 1, acc.y);
    atomicAdd(op + 2, acc.z);
    atomicAdd(op + 3, acc.w);
}

extern "C" void kernel_launch(void* const* d_in, const int* in_sizes, int n_in,
                              void* d_out, int out_size, void* d_ws, size_t ws_size,
                              hipStream_t stream) {
    const float* enc = (const float*)d_in[0];  // 32*2048*1024
    const float* dec = (const float*)d_in[1];  // 32*1*1024
    const float* w1  = (const float*)d_in[2];  // 1024*1024
    const float* b1  = (const float*)d_in[3];  // 1024
    const float* w2  = (const float*)d_in[4];  // 1024*1024
    const float* b2  = (const float*)d_in[5];  // 1024
    const float* v   = (const float*)d_in[6];  // 1024
    // d_in[7] = bv, softmax-invariant, unused
    float* out = (float*)d_out;                // 32*1024

    char* ws = (char*)d_ws;
    unsigned short* w1p = (unsigned short*)ws;                 // 2 MB
    float* qq     = (float*)(ws + (2u << 20));                 // 128 KB
    float* scores = (float*)(ws + (2u << 20) + (128u << 10));  // 256 KB
    float* attn   = scores + M_TOTAL;                          // 256 KB
    // total ws need: ~2.65 MB (small footprint keeps enc warm in L3)

    hipMemsetAsync(qq, 0, (128u << 10) + M_TOTAL * sizeof(float), stream);
    hipMemsetAsync(out, 0, 32 * 1024 * sizeof(float), stream);

    pack_w1<<<dim3(64, 32), 64, 0, stream>>>(w1, w1p);
    qq_kern<<<dim3(4, 32, 4), 256, 0, stream>>>(dec, w2, b1, b2, qq);
    score_gemm<<<1024, 512, 0, stream>>>(enc, w1p, qq, v, scores);
    softmax_kern<<<32, 256, 0, stream>>>(scores, attn);
    ctx_kern<<<dim3(32, 32), 256, 0, stream>>>(attn, enc, out);
}